// Round 2
// 1316.873 us; speedup vs baseline: 1.1345x; 1.1345x over previous
//
#include <hip/hip_runtime.h>
#include <hip/hip_bf16.h>
#include <math.h>

typedef unsigned short u16;
typedef unsigned int u32;
typedef __bf16 bf16x8 __attribute__((ext_vector_type(8)));
typedef float f32x4 __attribute__((ext_vector_type(4)));

__device__ __forceinline__ float bf2f(u16 h) {
    return __uint_as_float(((u32)h) << 16);
}
__device__ __forceinline__ u16 f2bf(float f) {
    u32 u = __float_as_uint(f);
    u32 r = (u + 0x7fffu + ((u >> 16) & 1u)) >> 16;
    return (u16)r;
}

__device__ __forceinline__ f32x4 mfma16(bf16x8 a, bf16x8 b, f32x4 c) {
    return __builtin_amdgcn_mfma_f32_16x16x32_bf16(a, b, c, 0, 0, 0);
}

// Async global->LDS, 16B per lane. LDS dest is wave-uniform base + lane*16;
// our staging layout is linear in t (byte off = t*16) so this is exact.
__device__ __forceinline__ void g2l(const u16* g, u16* l) {
    __builtin_amdgcn_global_load_lds(
        (const __attribute__((address_space(1))) unsigned int*)g,
        (__attribute__((address_space(3))) unsigned int*)l,
        16, 0, 0);
}

// ---------------------------------------------------------------------------
// Input dtype detection (flag=1 -> fp32) + canonicalization to bf16.
// ---------------------------------------------------------------------------
struct DetectArgs {
    const void* p[8];
    int n[8];
};

__global__ __launch_bounds__(256) void detect_k(DetectArgs a, u32* flags) {
    int b = blockIdx.x;
    int t = threadIdx.x;
    const u16* p = (const u16*)a.p[b];
    u16 v = p[2 * t];
    int e = (v >> 7) & 0xff;
    bool insane = (e < 87) || (e > 167);
    unsigned long long m = __ballot(insane);
    __shared__ u32 s[4];
    int w = t >> 6;
    if ((t & 63) == 0) s[w] = (m != 0ull) ? 1u : 0u;
    __syncthreads();
    if (t == 0) flags[b] = s[0] | s[1] | s[2] | s[3];
}

__global__ __launch_bounds__(256) void convert_k(
    const void* src, u16* dst, int n, const u32* flags, int fi)
{
    u32 f = flags[fi];
    int j0 = blockIdx.x * 1024 + threadIdx.x * 4;
    if (f) {
        const float* s = (const float*)src;
        for (int k = 0; k < 4; k++) {
            int j = j0 + k;
            if (j < n) dst[j] = f2bf(s[j]);
        }
    } else {
        const u16* s = (const u16*)src;
        for (int k = 0; k < 4; k++) {
            int j = j0 + k;
            if (j < n) dst[j] = s[j];
        }
    }
}

// ---------------------------------------------------------------------------
// Generic 128x128-tile GEMM: C = X(MxK) @ W(NxK)^T, bf16 in, fp32 accum.
// Output bf16 (Cb) or fp32 (Cf). Staging via global_load_lds (m97 structure).
// ---------------------------------------------------------------------------
__global__ __launch_bounds__(256) void gemm128(
    const u16* __restrict__ X, int xRow, long long xBat,
    const u16* __restrict__ W, int wRow, long long wBat,
    u16* __restrict__ Cb, float* __restrict__ Cf,
    int cRow, long long cBatB, long long cBatH,
    int N, int K)
{
    __shared__ __align__(16) u16 As[128 * 32];
    __shared__ __align__(16) u16 Bs[128 * 32];

    int z = blockIdx.z;
    const u16* Xz = X + (long long)z * xBat;
    const u16* Wz = W + (long long)z * wBat;
    long long cOff = (long long)(z >> 4) * cBatB + (long long)(z & 15) * cBatH;

    int t = threadIdx.x;
    int lane = t & 63, w = t >> 6;
    int sr = t >> 2;
    int sc = (t & 3) * 8;
    int m0 = blockIdx.y * 128, n0 = blockIdx.x * 128;
    int wr = (w >> 1) * 64, wc = (w & 1) * 64;
    int mrow = lane & 15, quad = lane >> 4;

    u16* As0 = &As[t * 8];
    u16* As1 = &As[2048 + t * 8];
    u16* Bs0 = &Bs[t * 8];
    u16* Bs1 = &Bs[2048 + t * 8];

    f32x4 zero = {0.f, 0.f, 0.f, 0.f};
    f32x4 acc[4][4];
    for (int i = 0; i < 4; i++)
        for (int j = 0; j < 4; j++) acc[i][j] = zero;

    for (int k0 = 0; k0 < K; k0 += 32) {
        const u16* ga0 = Xz + (long long)(m0 + sr) * xRow + k0 + sc;
        const u16* ga1 = ga0 + (long long)64 * xRow;
        int bn0 = n0 + sr;      if (bn0 >= N) bn0 = N - 1;
        int bn1 = n0 + sr + 64; if (bn1 >= N) bn1 = N - 1;
        const u16* gb0 = Wz + (long long)bn0 * wRow + k0 + sc;
        const u16* gb1 = Wz + (long long)bn1 * wRow + k0 + sc;
        __syncthreads();
        g2l(ga0, As0);
        g2l(ga1, As1);
        g2l(gb0, Bs0);
        g2l(gb1, Bs1);
        __syncthreads();

        bf16x8 af[4], bfr[4];
        for (int i = 0; i < 4; i++) {
            af[i]  = *(const bf16x8*)(&As[(wr + i * 16 + mrow) * 32 + quad * 8]);
            bfr[i] = *(const bf16x8*)(&Bs[(wc + i * 16 + mrow) * 32 + quad * 8]);
        }
        for (int mt = 0; mt < 4; mt++)
            for (int nt = 0; nt < 4; nt++)
                acc[mt][nt] = mfma16(af[mt], bfr[nt], acc[mt][nt]);
    }

    for (int mt = 0; mt < 4; mt++)
        for (int nt = 0; nt < 4; nt++)
            for (int r = 0; r < 4; r++) {
                int row = m0 + wr + mt * 16 + quad * 4 + r;
                int col = n0 + wc + nt * 16 + mrow;
                if (col < N) {
                    long long idx = cOff + (long long)row * cRow + col;
                    float v = acc[mt][nt][r];
                    if (Cb) Cb[idx] = f2bf(v); else Cf[idx] = v;
                }
            }
}

// ---------------------------------------------------------------------------
// GEMM variant: X is fp32 (converted to bf16 while staging to LDS), W bf16.
// C = X(MxK) @ W(NxK)^T -> bf16. Used for O = attn(fp32 probs) @ V.
// Causal: attn[row][k]==0 for k>row, so K-loop stops at m0+128.
// B-side staged via global_load_lds.
// ---------------------------------------------------------------------------
__global__ __launch_bounds__(256) void gemm128_xf32(
    const float* __restrict__ X, int xRow, long long xBat,
    const u16* __restrict__ W, int wRow, long long wBat,
    u16* __restrict__ Cb, int cRow, long long cBatB, long long cBatH,
    int N, int K)
{
    __shared__ __align__(16) u16 As[128 * 32];
    __shared__ __align__(16) u16 Bs[128 * 32];

    int z = blockIdx.z;
    const float* Xz = X + (long long)z * xBat;
    const u16* Wz = W + (long long)z * wBat;
    long long cOff = (long long)(z >> 4) * cBatB + (long long)(z & 15) * cBatH;

    int t = threadIdx.x;
    int lane = t & 63, w = t >> 6;
    int sr = t >> 2;
    int sc = (t & 3) * 8;
    int m0 = blockIdx.y * 128, n0 = blockIdx.x * 128;
    int wr = (w >> 1) * 64, wc = (w & 1) * 64;
    int mrow = lane & 15, quad = lane >> 4;

    u16* Bs0 = &Bs[t * 8];
    u16* Bs1 = &Bs[2048 + t * 8];

    f32x4 zero = {0.f, 0.f, 0.f, 0.f};
    f32x4 acc[4][4];
    for (int i = 0; i < 4; i++)
        for (int j = 0; j < 4; j++) acc[i][j] = zero;

    int kEnd = m0 + 128; if (kEnd > K) kEnd = K;   // causal upper bound

    for (int k0 = 0; k0 < kEnd; k0 += 32) {
        const float* ap0 = Xz + (long long)(m0 + sr) * xRow + k0 + sc;
        const float* ap1 = Xz + (long long)(m0 + sr + 64) * xRow + k0 + sc;
        float4 a0l = *(const float4*)(ap0), a0h = *(const float4*)(ap0 + 4);
        float4 a1l = *(const float4*)(ap1), a1h = *(const float4*)(ap1 + 4);
        int bn0 = n0 + sr;      if (bn0 >= N) bn0 = N - 1;
        int bn1 = n0 + sr + 64; if (bn1 >= N) bn1 = N - 1;
        const u16* gb0 = Wz + (long long)bn0 * wRow + k0 + sc;
        const u16* gb1 = Wz + (long long)bn1 * wRow + k0 + sc;
        u16 pa0[8] = {f2bf(a0l.x), f2bf(a0l.y), f2bf(a0l.z), f2bf(a0l.w),
                      f2bf(a0h.x), f2bf(a0h.y), f2bf(a0h.z), f2bf(a0h.w)};
        u16 pa1[8] = {f2bf(a1l.x), f2bf(a1l.y), f2bf(a1l.z), f2bf(a1l.w),
                      f2bf(a1h.x), f2bf(a1h.y), f2bf(a1h.z), f2bf(a1h.w)};
        __syncthreads();
        *(uint4*)(&As[sr * 32 + sc]) = *(const uint4*)pa0;
        *(uint4*)(&As[(sr + 64) * 32 + sc]) = *(const uint4*)pa1;
        g2l(gb0, Bs0);
        g2l(gb1, Bs1);
        __syncthreads();

        bf16x8 af[4], bfr[4];
        for (int i = 0; i < 4; i++) {
            af[i]  = *(const bf16x8*)(&As[(wr + i * 16 + mrow) * 32 + quad * 8]);
            bfr[i] = *(const bf16x8*)(&Bs[(wc + i * 16 + mrow) * 32 + quad * 8]);
        }
        for (int mt = 0; mt < 4; mt++)
            for (int nt = 0; nt < 4; nt++)
                acc[mt][nt] = mfma16(af[mt], bfr[nt], acc[mt][nt]);
    }

    for (int mt = 0; mt < 4; mt++)
        for (int nt = 0; nt < 4; nt++)
            for (int r = 0; r < 4; r++) {
                int row = m0 + wr + mt * 16 + quad * 4 + r;
                int col = n0 + wc + nt * 16 + mrow;
                if (col < N)
                    Cb[cOff + (long long)row * cRow + col] = f2bf(acc[mt][nt][r]);
            }
}

// ---------------------------------------------------------------------------
// RMS norm over fp32 rows -> bf16
// ---------------------------------------------------------------------------
__global__ __launch_bounds__(256) void rmsnorm_k(
    const float* __restrict__ in, int inRow,
    const u16* __restrict__ wgt,
    u16* __restrict__ out, int outRow, int len)
{
    int row = blockIdx.x;
    const float* x = in + (long long)row * inRow;
    u16* o = out + (long long)row * outRow;
    int t = threadIdx.x;
    float ss = 0.f;
    for (int j = t; j < len; j += 256) { float v = x[j]; ss += v * v; }
    for (int s = 1; s < 64; s <<= 1) ss += __shfl_xor(ss, s);
    __shared__ float red[4];
    int w = t >> 6, lane = t & 63;
    if (lane == 0) red[w] = ss;
    __syncthreads();
    float tot = red[0] + red[1] + red[2] + red[3];
    float r = rsqrtf(tot / (float)len + 1e-6f);
    for (int j = t; j < len; j += 256)
        o[j] = f2bf(bf2f(wgt[j]) * (x[j] * r));
}

// ---------------------------------------------------------------------------
// Rope: deinterleave + rotate.
// ---------------------------------------------------------------------------
__device__ __forceinline__ void rope64(const float* xin, float* xo, int pos) {
    for (int i = 0; i < 32; i++) {
        float ex = (float)(2 * i) * (1.0f / 64.0f);
        float invf = expf(-ex * 9.210340371976184f);  // 10000^-ex
        float ang = (float)pos * invf;
        float sn, cs;
        sincosf(ang, &sn, &cs);
        float a = xin[2 * i], b = xin[2 * i + 1];
        xo[i] = a * cs - b * sn;
        xo[32 + i] = b * cs + a * sn;
    }
}

__global__ __launch_bounds__(256) void rope_q_k(u16* __restrict__ qf) {
    int idx = blockIdx.x * 256 + threadIdx.x;   // 4096*16
    int row = idx >> 4, h = idx & 15, pos = row & 2047;
    u16* p = qf + (long long)row * 3072 + h * 192 + 128;
    float xin[64], xo[64];
    for (int j = 0; j < 64; j++) xin[j] = bf2f(p[j]);
    rope64(xin, xo, pos);
    for (int j = 0; j < 64; j++) p[j] = f2bf(xo[j]);
}

__global__ __launch_bounds__(256) void rope_kk(
    const float* __restrict__ cpre, u16* __restrict__ kr) {
    int row = blockIdx.x * 256 + threadIdx.x;   // 4096
    int pos = row & 2047;
    const float* src = cpre + (long long)row * 576 + 512;
    float xin[64], xo[64];
    for (int j = 0; j < 64; j++) xin[j] = src[j];
    rope64(xin, xo, pos);
    u16* dst = kr + (long long)row * 64;
    for (int j = 0; j < 64; j++) dst[j] = f2bf(xo[j]);
}

// ---------------------------------------------------------------------------
// V^T materialization: Vt[bh][d][s] = kv_up[b*2048+s][h*256+128+d]
// ---------------------------------------------------------------------------
__global__ void transpose_v(const u16* __restrict__ kvup, u16* __restrict__ Vt) {
    __shared__ u16 tile[32][33];
    int bh = blockIdx.z, b = bh >> 4, h = bh & 15;
    int s0 = blockIdx.x * 32, d0 = blockIdx.y * 32;
    int tx = threadIdx.x, ty = threadIdx.y;   // (32,8)
    for (int i = 0; i < 4; i++) {
        int s = s0 + ty + i * 8;
        tile[ty + i * 8][tx] = kvup[(long long)(b * 2048 + s) * 4096 + h * 256 + 128 + d0 + tx];
    }
    __syncthreads();
    for (int i = 0; i < 4; i++) {
        int d = d0 + ty + i * 8;
        Vt[((long long)bh * 128 + d) * 2048 + s0 + tx] = tile[tx][ty + i * 8];
    }
}

#define ATTN_SCALE 0.07216878364870323f   // 1/sqrt(192)

// ---------------------------------------------------------------------------
// Raw scaled scores S = (Q K^T) * scale -> attn region (fp32), m97-structure
// staging, K=192 from kv_up(nope) + krope(rope). Blocks above diagonal skip.
// ---------------------------------------------------------------------------
__global__ __launch_bounds__(256) void scores_gemm(
    const u16* __restrict__ qf, const u16* __restrict__ kvup,
    const u16* __restrict__ krope, float* __restrict__ attn)
{
    int n0 = blockIdx.x * 128, q0 = blockIdx.y * 128;
    if (n0 > q0) return;
    int bh = blockIdx.z, b = bh >> 4, h = bh & 15;
    const u16* qb = qf + (long long)b * 2048 * 3072 + h * 192;
    const u16* kn = kvup + (long long)b * 2048 * 4096 + h * 256;
    const u16* kr = krope + (long long)b * 2048 * 64;
    long long abase = (long long)bh * 4194304;

    __shared__ __align__(16) u16 As[128 * 32];
    __shared__ __align__(16) u16 Bs[128 * 32];
    int t = threadIdx.x, lane = t & 63, w = t >> 6;
    int sr = t >> 2, sc = (t & 3) * 8;
    int wr = (w >> 1) * 64, wc = (w & 1) * 64;
    int mrow = lane & 15, quad = lane >> 4;

    u16* As0 = &As[t * 8];
    u16* As1 = &As[2048 + t * 8];
    u16* Bs0 = &Bs[t * 8];
    u16* Bs1 = &Bs[2048 + t * 8];

    f32x4 zero = {0.f, 0.f, 0.f, 0.f};
    f32x4 acc[4][4];
    for (int i = 0; i < 4; i++)
        for (int j = 0; j < 4; j++) acc[i][j] = zero;

    for (int k0 = 0; k0 < 192; k0 += 32) {
        const u16* ga0 = qb + (long long)(q0 + sr) * 3072 + k0 + sc;
        const u16* ga1 = ga0 + (long long)64 * 3072;
        const u16 *gb0, *gb1;
        if (k0 < 128) {
            gb0 = kn + (long long)(n0 + sr) * 4096 + k0 + sc;
            gb1 = gb0 + (long long)64 * 4096;
        } else {
            gb0 = kr + (long long)(n0 + sr) * 64 + (k0 - 128) + sc;
            gb1 = gb0 + (long long)64 * 64;
        }
        __syncthreads();
        g2l(ga0, As0);
        g2l(ga1, As1);
        g2l(gb0, Bs0);
        g2l(gb1, Bs1);
        __syncthreads();

        bf16x8 af[4], bfr[4];
        for (int i = 0; i < 4; i++) {
            af[i]  = *(const bf16x8*)(&As[(wr + i * 16 + mrow) * 32 + quad * 8]);
            bfr[i] = *(const bf16x8*)(&Bs[(wc + i * 16 + mrow) * 32 + quad * 8]);
        }
        for (int mt = 0; mt < 4; mt++)
            for (int nt = 0; nt < 4; nt++)
                acc[mt][nt] = mfma16(af[mt], bfr[nt], acc[mt][nt]);
    }

    for (int mt = 0; mt < 4; mt++)
        for (int nt = 0; nt < 4; nt++)
            for (int r = 0; r < 4; r++) {
                int row = q0 + wr + mt * 16 + quad * 4 + r;
                int col = n0 + wc + nt * 16 + mrow;
                attn[abase + (long long)row * 2048 + col] = acc[mt][nt][r] * ATTN_SCALE;
            }
}

// ---------------------------------------------------------------------------
// Row-wise causal softmax, in place over the fp32 attn region.
// Single read + single write: the whole row (<=2048) lives in 8 regs/thread.
// ---------------------------------------------------------------------------
__global__ __launch_bounds__(256) void softmax_rows(float* __restrict__ attn) {
    int r = blockIdx.x;
    long long bh = blockIdx.y;
    float* p = attn + bh * 4194304LL + (long long)r * 2048;
    int t = threadIdx.x;
    int valid = r + 1;
    int j0 = t * 4;

    float v[8];
    float mx = -INFINITY;
#pragma unroll
    for (int h = 0; h < 2; h++) {
        int j = j0 + h * 1024;
        if (j + 4 <= valid) {
            float4 q = *(const float4*)(p + j);
            v[h * 4 + 0] = q.x; v[h * 4 + 1] = q.y;
            v[h * 4 + 2] = q.z; v[h * 4 + 3] = q.w;
        } else {
#pragma unroll
            for (int k = 0; k < 4; k++) {
                int jj = j + k;
                v[h * 4 + k] = (jj < valid) ? p[jj] : -INFINITY;
            }
        }
#pragma unroll
        for (int k = 0; k < 4; k++) mx = fmaxf(mx, v[h * 4 + k]);
    }
    for (int s = 1; s < 64; s <<= 1) mx = fmaxf(mx, __shfl_xor(mx, s));
    __shared__ float sm[4], s2[4];
    int w = t >> 6;
    if ((t & 63) == 0) sm[w] = mx;
    __syncthreads();
    mx = fmaxf(fmaxf(sm[0], sm[1]), fmaxf(sm[2], sm[3]));

    float ss = 0.f;
#pragma unroll
    for (int i = 0; i < 8; i++) {
        float e = (v[i] == -INFINITY) ? 0.f : expf(v[i] - mx);
        v[i] = e;
        ss += e;
    }
    for (int s = 1; s < 64; s <<= 1) ss += __shfl_xor(ss, s);
    if ((t & 63) == 0) s2[w] = ss;
    __syncthreads();
    ss = s2[0] + s2[1] + s2[2] + s2[3];
    float inv = 1.0f / ss;

#pragma unroll
    for (int h = 0; h < 2; h++) {
        float4 q;
        q.x = v[h * 4 + 0] * inv;
        q.y = v[h * 4 + 1] * inv;
        q.z = v[h * 4 + 2] * inv;
        q.w = v[h * 4 + 3] * inv;
        *(float4*)(p + j0 + h * 1024) = q;
    }
}

// ---------------------------------------------------------------------------
extern "C" void kernel_launch(void* const* d_in, const int* in_sizes, int n_in,
                              void* d_out, int out_size, void* d_ws, size_t ws_size,
                              hipStream_t stream) {
    (void)in_sizes; (void)n_in; (void)out_size; (void)ws_size;

    const void* r_hidden = d_in[0];
    const void* r_wqd    = d_in[3];
    const void* r_qnw    = d_in[4];
    const void* r_wqu    = d_in[5];
    const void* r_wkvd   = d_in[6];
    const void* r_kvnw   = d_in[7];
    const void* r_wkvu   = d_in[8];
    const void* r_wout   = d_in[9];

    float* out_p  = (float*)d_out;                   // (4096, 2048) fp32
    float* attn_p = (float*)d_out + 8388608LL;       // (32, 2048, 2048) fp32

    char* ws = (char*)d_ws;
    size_t off = 0;
    auto alloc = [&](size_t bytes) { void* p = ws + off; off = (off + bytes + 255) & ~(size_t)255; return p; };

    u32* flags = (u32*)alloc(256);
    // regionA: q_pre fp32 + c_pre fp32; kv_up bf16 aliases after both dead
    char* regionA = (char*)alloc(25165824 + 9437184);
    float* q_pre = (float*)regionA;                  // 4096 x 1536 fp32
    float* c_pre = (float*)(regionA + 25165824);     // 4096 x 576  fp32
    u16* kv_up   = (u16*)regionA;                    // 4096 x 4096 bf16 (33.5MB <= 34.6MB)
    // regionB: hidden_c; Vt aliases after hidden dead (both exactly 16MB)
    char* regionB = (char*)alloc(16777216);
    u16* hidden_c = (u16*)regionB;                   // 4096 x 2048
    u16* Vt       = (u16*)regionB;                   // 32 x 128 x 2048
    // regionC: q_c; kv_c + krope alias after q_c dead
    char* regionC = (char*)alloc(12582912);
    u16* q_c   = (u16*)regionC;                      // 4096 x 1536
    u16* kv_c  = (u16*)regionC;                      // 4096 x 512 (4.19MB)
    u16* krope = (u16*)(regionC + 4194304);          // 4096 x 64  (0.52MB)
    u16* wqd_c  = (u16*)alloc(1536LL * 2048 * 2);
    u16* qnw_c  = (u16*)alloc(1536LL * 2);
    u16* wqu_c  = (u16*)alloc(3072LL * 1536 * 2);
    u16* wkvd_c = (u16*)alloc(576LL * 2048 * 2);
    u16* kvnw_c = (u16*)alloc(512LL * 2);
    u16* wkvu_c = (u16*)alloc(4096LL * 512 * 2);
    u16* wout_c = (u16*)alloc(2048LL * 2048 * 2);
    u16* q_full = (u16*)alloc(4096LL * 3072 * 2);    // Obuf aliases after scores
    u16* Obuf   = q_full;                            // 16.8MB <= 25.2MB

    // --- dtype detection + canonicalization to bf16 ---
    DetectArgs da;
    da.p[0] = r_hidden; da.n[0] = 8388608;
    da.p[1] = r_wqd;    da.n[1] = 3145728;
    da.p[2] = r_qnw;    da.n[2] = 1536;
    da.p[3] = r_wqu;    da.n[3] = 4718592;
    da.p[4] = r_wkvd;   da.n[4] = 1179648;
    da.p[5] = r_kvnw;   da.n[5] = 512;
    da.p[6] = r_wkvu;   da.n[6] = 2097152;
    da.p[7] = r_wout;   da.n[7] = 4194304;
    hipLaunchKernelGGL(detect_k, dim3(8), dim3(256), 0, stream, da, flags);

    const void* srcs[8] = {r_hidden, r_wqd, r_qnw, r_wqu, r_wkvd, r_kvnw, r_wkvu, r_wout};
    u16* dsts[8] = {hidden_c, wqd_c, qnw_c, wqu_c, wkvd_c, kvnw_c, wkvu_c, wout_c};
    for (int i = 0; i < 8; i++) {
        int n = da.n[i];
        hipLaunchKernelGGL(convert_k, dim3((n + 1023) / 1024), dim3(256), 0, stream,
            srcs[i], dsts[i], n, flags, i);
    }

    // 1. q_pre = hidden @ w_q_down^T (fp32)
    hipLaunchKernelGGL(gemm128, dim3(12, 32, 1), dim3(256), 0, stream,
        hidden_c, 2048, 0LL, wqd_c, 2048, 0LL, (u16*)nullptr, q_pre, 1536, 0LL, 0LL, 1536, 2048);
    // 2. q_c = rmsnorm(q_pre)
    hipLaunchKernelGGL(rmsnorm_k, dim3(4096), dim3(256), 0, stream,
        q_pre, 1536, qnw_c, q_c, 1536, 1536);
    // 3. q_full = q_c @ w_q_up^T
    hipLaunchKernelGGL(gemm128, dim3(24, 32, 1), dim3(256), 0, stream,
        q_c, 1536, 0LL, wqu_c, 1536, 0LL, q_full, (float*)nullptr, 3072, 0LL, 0LL, 3072, 1536);
    // 4. rope on q (in place)
    hipLaunchKernelGGL(rope_q_k, dim3(256), dim3(256), 0, stream, q_full);
    // 5. c_pre = hidden @ w_kv_down^T (fp32)
    hipLaunchKernelGGL(gemm128, dim3(5, 32, 1), dim3(256), 0, stream,
        hidden_c, 2048, 0LL, wkvd_c, 2048, 0LL, (u16*)nullptr, c_pre, 576, 0LL, 0LL, 576, 2048);
    // 6. kv_c = rmsnorm(c_pre[:, :512])   (q_c dead -> regionC reuse)
    hipLaunchKernelGGL(rmsnorm_k, dim3(4096), dim3(256), 0, stream,
        c_pre, 576, kvnw_c, kv_c, 512, 512);
    // 7. k_rope = rope(c_pre[:, 512:])
    hipLaunchKernelGGL(rope_kk, dim3(16), dim3(256), 0, stream, c_pre, krope);
    // 8. kv_up = kv_c @ w_kv_up^T (regionA reuse; q_pre/c_pre dead)
    hipLaunchKernelGGL(gemm128, dim3(32, 32, 1), dim3(256), 0, stream,
        kv_c, 512, 0LL, wkvu_c, 512, 0LL, kv_up, (float*)nullptr, 4096, 0LL, 0LL, 4096, 512);
    // 9. Vt[bh][d][s]  (regionB reuse; hidden dead)
    hipLaunchKernelGGL(transpose_v, dim3(64, 4, 32), dim3(32, 8), 0, stream, kv_up, Vt);
    // 10. raw scaled scores -> attn region (fp32)
    hipLaunchKernelGGL(scores_gemm, dim3(16, 16, 32), dim3(256), 0, stream,
        q_full, kv_up, krope, attn_p);
    // 11. row-wise causal softmax in place (fp32)
    hipLaunchKernelGGL(softmax_rows, dim3(2048, 32), dim3(256), 0, stream, attn_p);
    // 12. O = attn @ V (batched over bh); fp32 probs -> bf16 at staging
    hipLaunchKernelGGL(gemm128_xf32, dim3(1, 16, 32), dim3(256), 0, stream,
        attn_p, 2048, 4194304LL, Vt, 2048, 262144LL, Obuf,
        2048, 4194304LL, 128LL, 128, 2048);
    // 13. out = O @ w_out^T (fp32 out)
    hipLaunchKernelGGL(gemm128, dim3(16, 32, 1), dim3(256), 0, stream,
        Obuf, 2048, 0LL, wout_c, 2048, 0LL, (u16*)nullptr, out_p, 2048, 0LL, 0LL, 2048, 2048);
}

// Round 5
// 1260.590 us; speedup vs baseline: 1.1851x; 1.0446x over previous
//
#include <hip/hip_runtime.h>
#include <hip/hip_bf16.h>
#include <math.h>

typedef unsigned short u16;
typedef unsigned int u32;
typedef __bf16 bf16x8 __attribute__((ext_vector_type(8)));
typedef float f32x4 __attribute__((ext_vector_type(4)));

__device__ __forceinline__ float bf2f(u16 h) {
    return __uint_as_float(((u32)h) << 16);
}
__device__ __forceinline__ u16 f2bf(float f) {
    u32 u = __float_as_uint(f);
    u32 r = (u + 0x7fffu + ((u >> 16) & 1u)) >> 16;
    return (u16)r;
}

__device__ __forceinline__ f32x4 mfma16(bf16x8 a, bf16x8 b, f32x4 c) {
    return __builtin_amdgcn_mfma_f32_16x16x32_bf16(a, b, c, 0, 0, 0);
}

// Async global->LDS, 16B per lane. LDS dest is wave-uniform base + lane*16.
__device__ __forceinline__ void g2l(const u16* g, u16* l) {
    __builtin_amdgcn_global_load_lds(
        (const __attribute__((address_space(1))) unsigned int*)g,
        (__attribute__((address_space(3))) unsigned int*)l,
        16, 0, 0);
}

// ---------------------------------------------------------------------------
// Input dtype detection (flag=1 -> fp32) + canonicalization to bf16.
// ---------------------------------------------------------------------------
struct DetectArgs {
    const void* p[8];
    int n[8];
};

__global__ __launch_bounds__(256) void detect_k(DetectArgs a, u32* flags) {
    int b = blockIdx.x;
    int t = threadIdx.x;
    const u16* p = (const u16*)a.p[b];
    u16 v = p[2 * t];
    int e = (v >> 7) & 0xff;
    bool insane = (e < 87) || (e > 167);
    unsigned long long m = __ballot(insane);
    __shared__ u32 s[4];
    int w = t >> 6;
    if ((t & 63) == 0) s[w] = (m != 0ull) ? 1u : 0u;
    __syncthreads();
    if (t == 0) flags[b] = s[0] | s[1] | s[2] | s[3];
}

// All 8 tensors in one dispatch; block -> tensor via prefix table (uniform scan).
struct ConvArgs {
    const void* src[8];
    u16* dst[8];
    int n[8];
    int pre[9];
};

__global__ __launch_bounds__(256) void convert_all(ConvArgs a, const u32* flags) {
    int bx = blockIdx.x;
    int i = 0;
    while (i < 7 && bx >= a.pre[i + 1]) i++;
    int lb = bx - a.pre[i];
    int n = a.n[i];
    u32 f = flags[i];
    const void* src = a.src[i];
    u16* dst = a.dst[i];
    int j0 = lb * 1024 + threadIdx.x * 4;
    if (f) {
        const float* s = (const float*)src;
        for (int k = 0; k < 4; k++) {
            int j = j0 + k;
            if (j < n) dst[j] = f2bf(s[j]);
        }
    } else {
        const u16* s = (const u16*)src;
        for (int k = 0; k < 4; k++) {
            int j = j0 + k;
            if (j < n) dst[j] = s[j];
        }
    }
}

// ---------------------------------------------------------------------------
// Generic 128x128-tile GEMM: C = X(MxK) @ W(NxK)^T, bf16 in, fp32 accum.
// Output bf16 (Cb) or fp32 (Cf). Staging via global_load_lds (m97 structure).
// ---------------------------------------------------------------------------
__global__ __launch_bounds__(256) void gemm128(
    const u16* __restrict__ X, int xRow, long long xBat,
    const u16* __restrict__ W, int wRow, long long wBat,
    u16* __restrict__ Cb, float* __restrict__ Cf,
    int cRow, long long cBatB, long long cBatH,
    int N, int K)
{
    __shared__ __align__(16) u16 As[128 * 32];
    __shared__ __align__(16) u16 Bs[128 * 32];

    int z = blockIdx.z;
    const u16* Xz = X + (long long)z * xBat;
    const u16* Wz = W + (long long)z * wBat;
    long long cOff = (long long)(z >> 4) * cBatB + (long long)(z & 15) * cBatH;

    int t = threadIdx.x;
    int lane = t & 63, w = t >> 6;
    int sr = t >> 2;
    int sc = (t & 3) * 8;
    int m0 = blockIdx.y * 128, n0 = blockIdx.x * 128;
    int wr = (w >> 1) * 64, wc = (w & 1) * 64;
    int mrow = lane & 15, quad = lane >> 4;

    u16* As0 = &As[t * 8];
    u16* As1 = &As[2048 + t * 8];
    u16* Bs0 = &Bs[t * 8];
    u16* Bs1 = &Bs[2048 + t * 8];

    f32x4 zero = {0.f, 0.f, 0.f, 0.f};
    f32x4 acc[4][4];
    for (int i = 0; i < 4; i++)
        for (int j = 0; j < 4; j++) acc[i][j] = zero;

    for (int k0 = 0; k0 < K; k0 += 32) {
        const u16* ga0 = Xz + (long long)(m0 + sr) * xRow + k0 + sc;
        const u16* ga1 = ga0 + (long long)64 * xRow;
        int bn0 = n0 + sr;      if (bn0 >= N) bn0 = N - 1;
        int bn1 = n0 + sr + 64; if (bn1 >= N) bn1 = N - 1;
        const u16* gb0 = Wz + (long long)bn0 * wRow + k0 + sc;
        const u16* gb1 = Wz + (long long)bn1 * wRow + k0 + sc;
        __syncthreads();
        g2l(ga0, As0);
        g2l(ga1, As1);
        g2l(gb0, Bs0);
        g2l(gb1, Bs1);
        __syncthreads();

        bf16x8 af[4], bfr[4];
        for (int i = 0; i < 4; i++) {
            af[i]  = *(const bf16x8*)(&As[(wr + i * 16 + mrow) * 32 + quad * 8]);
            bfr[i] = *(const bf16x8*)(&Bs[(wc + i * 16 + mrow) * 32 + quad * 8]);
        }
        for (int mt = 0; mt < 4; mt++)
            for (int nt = 0; nt < 4; nt++)
                acc[mt][nt] = mfma16(af[mt], bfr[nt], acc[mt][nt]);
    }

    for (int mt = 0; mt < 4; mt++)
        for (int nt = 0; nt < 4; nt++)
            for (int r = 0; r < 4; r++) {
                int row = m0 + wr + mt * 16 + quad * 4 + r;
                int col = n0 + wc + nt * 16 + mrow;
                if (col < N) {
                    long long idx = cOff + (long long)row * cRow + col;
                    float v = acc[mt][nt][r];
                    if (Cb) Cb[idx] = f2bf(v); else Cf[idx] = v;
                }
            }
}

// ---------------------------------------------------------------------------
// Dual-GEMM: two independent bf16 GEMMs (q_up and kv_up) in one dispatch,
// selected by blockIdx.z. Same 128x128 m97 structure; batch=1, bf16 out.
// ---------------------------------------------------------------------------
struct DualGemm {
    const u16* X[2]; int xRow[2];
    const u16* W[2]; int wRow[2];
    u16* C[2];       int cRow[2];
    int N[2]; int K[2]; int xmax[2];
};

__global__ __launch_bounds__(256) void gemm128_dual(DualGemm d) {
    int s = blockIdx.z;
    if ((int)blockIdx.x >= d.xmax[s]) return;
    const u16* __restrict__ X = d.X[s]; int xRow = d.xRow[s];
    const u16* __restrict__ W = d.W[s]; int wRow = d.wRow[s];
    u16* __restrict__ Cb = d.C[s];      int cRow = d.cRow[s];
    int N = d.N[s], K = d.K[s];

    __shared__ __align__(16) u16 As[128 * 32];
    __shared__ __align__(16) u16 Bs[128 * 32];

    int t = threadIdx.x;
    int lane = t & 63, w = t >> 6;
    int sr = t >> 2;
    int sc = (t & 3) * 8;
    int m0 = blockIdx.y * 128, n0 = blockIdx.x * 128;
    int wr = (w >> 1) * 64, wc = (w & 1) * 64;
    int mrow = lane & 15, quad = lane >> 4;

    u16* As0 = &As[t * 8];
    u16* As1 = &As[2048 + t * 8];
    u16* Bs0 = &Bs[t * 8];
    u16* Bs1 = &Bs[2048 + t * 8];

    f32x4 zero = {0.f, 0.f, 0.f, 0.f};
    f32x4 acc[4][4];
    for (int i = 0; i < 4; i++)
        for (int j = 0; j < 4; j++) acc[i][j] = zero;

    for (int k0 = 0; k0 < K; k0 += 32) {
        const u16* ga0 = X + (long long)(m0 + sr) * xRow + k0 + sc;
        const u16* ga1 = ga0 + (long long)64 * xRow;
        const u16* gb0 = W + (long long)(n0 + sr) * wRow + k0 + sc;
        const u16* gb1 = gb0 + (long long)64 * wRow;
        __syncthreads();
        g2l(ga0, As0);
        g2l(ga1, As1);
        g2l(gb0, Bs0);
        g2l(gb1, Bs1);
        __syncthreads();

        bf16x8 af[4], bfr[4];
        for (int i = 0; i < 4; i++) {
            af[i]  = *(const bf16x8*)(&As[(wr + i * 16 + mrow) * 32 + quad * 8]);
            bfr[i] = *(const bf16x8*)(&Bs[(wc + i * 16 + mrow) * 32 + quad * 8]);
        }
        for (int mt = 0; mt < 4; mt++)
            for (int nt = 0; nt < 4; nt++)
                acc[mt][nt] = mfma16(af[mt], bfr[nt], acc[mt][nt]);
    }

    for (int mt = 0; mt < 4; mt++)
        for (int nt = 0; nt < 4; nt++)
            for (int r = 0; r < 4; r++) {
                int row = m0 + wr + mt * 16 + quad * 4 + r;
                int col = n0 + wc + nt * 16 + mrow;
                Cb[(long long)row * cRow + col] = f2bf(acc[mt][nt][r]);
            }
}

// ---------------------------------------------------------------------------
// GEMM variant: X is fp32 (converted to bf16 while staging to LDS), W bf16.
// C = X(MxK) @ W(NxK)^T -> bf16. Used for O = attn(fp32 probs) @ V.
// Causal: attn[row][k]==0 for k>row, so K-loop stops at m0+128.
// Heavy tiles first: m0 reversed so big-K blocks start early (tail packing).
// ---------------------------------------------------------------------------
__global__ __launch_bounds__(256) void gemm128_xf32(
    const float* __restrict__ X, int xRow, long long xBat,
    const u16* __restrict__ W, int wRow, long long wBat,
    u16* __restrict__ Cb, int cRow, long long cBatB, long long cBatH,
    int N, int K)
{
    __shared__ __align__(16) u16 As[128 * 32];
    __shared__ __align__(16) u16 Bs[128 * 32];

    int z = blockIdx.z;
    const float* Xz = X + (long long)z * xBat;
    const u16* Wz = W + (long long)z * wBat;
    long long cOff = (long long)(z >> 4) * cBatB + (long long)(z & 15) * cBatH;

    int t = threadIdx.x;
    int lane = t & 63, w = t >> 6;
    int sr = t >> 2;
    int sc = (t & 3) * 8;
    int m0 = ((int)gridDim.y - 1 - (int)blockIdx.y) * 128;   // heavy first
    int n0 = blockIdx.x * 128;
    int wr = (w >> 1) * 64, wc = (w & 1) * 64;
    int mrow = lane & 15, quad = lane >> 4;

    u16* Bs0 = &Bs[t * 8];
    u16* Bs1 = &Bs[2048 + t * 8];

    f32x4 zero = {0.f, 0.f, 0.f, 0.f};
    f32x4 acc[4][4];
    for (int i = 0; i < 4; i++)
        for (int j = 0; j < 4; j++) acc[i][j] = zero;

    int kEnd = m0 + 128; if (kEnd > K) kEnd = K;   // causal upper bound

    for (int k0 = 0; k0 < kEnd; k0 += 32) {
        const float* ap0 = Xz + (long long)(m0 + sr) * xRow + k0 + sc;
        const float* ap1 = Xz + (long long)(m0 + sr + 64) * xRow + k0 + sc;
        float4 a0l = *(const float4*)(ap0), a0h = *(const float4*)(ap0 + 4);
        float4 a1l = *(const float4*)(ap1), a1h = *(const float4*)(ap1 + 4);
        int bn0 = n0 + sr;      if (bn0 >= N) bn0 = N - 1;
        int bn1 = n0 + sr + 64; if (bn1 >= N) bn1 = N - 1;
        const u16* gb0 = Wz + (long long)bn0 * wRow + k0 + sc;
        const u16* gb1 = Wz + (long long)bn1 * wRow + k0 + sc;
        u16 pa0[8] = {f2bf(a0l.x), f2bf(a0l.y), f2bf(a0l.z), f2bf(a0l.w),
                      f2bf(a0h.x), f2bf(a0h.y), f2bf(a0h.z), f2bf(a0h.w)};
        u16 pa1[8] = {f2bf(a1l.x), f2bf(a1l.y), f2bf(a1l.z), f2bf(a1l.w),
                      f2bf(a1h.x), f2bf(a1h.y), f2bf(a1h.z), f2bf(a1h.w)};
        __syncthreads();
        *(uint4*)(&As[sr * 32 + sc]) = *(const uint4*)pa0;
        *(uint4*)(&As[(sr + 64) * 32 + sc]) = *(const uint4*)pa1;
        g2l(gb0, Bs0);
        g2l(gb1, Bs1);
        __syncthreads();

        bf16x8 af[4], bfr[4];
        for (int i = 0; i < 4; i++) {
            af[i]  = *(const bf16x8*)(&As[(wr + i * 16 + mrow) * 32 + quad * 8]);
            bfr[i] = *(const bf16x8*)(&Bs[(wc + i * 16 + mrow) * 32 + quad * 8]);
        }
        for (int mt = 0; mt < 4; mt++)
            for (int nt = 0; nt < 4; nt++)
                acc[mt][nt] = mfma16(af[mt], bfr[nt], acc[mt][nt]);
    }

    for (int mt = 0; mt < 4; mt++)
        for (int nt = 0; nt < 4; nt++)
            for (int r = 0; r < 4; r++) {
                int row = m0 + wr + mt * 16 + quad * 4 + r;
                int col = n0 + wc + nt * 16 + mrow;
                if (col < N)
                    Cb[cOff + (long long)row * cRow + col] = f2bf(acc[mt][nt][r]);
            }
}

// ---------------------------------------------------------------------------
// Merged RMS norm: y=0 -> q (len 1536), y=1 -> kv (len 512). Input rows from
// the merged down-projection (stride 2112 fp32). q_c and kv_c must NOT alias.
// ---------------------------------------------------------------------------
__global__ __launch_bounds__(256) void rmsnorm2_k(
    const float* __restrict__ base,
    const u16* __restrict__ qw, const u16* __restrict__ kw,
    u16* __restrict__ qo, u16* __restrict__ ko)
{
    int row = blockIdx.x;
    const float* x;
    const u16* wgt;
    u16* o;
    int len;
    if (blockIdx.y == 0) {
        x = base + (long long)row * 2112;       wgt = qw;
        o = qo + (long long)row * 1536;         len = 1536;
    } else {
        x = base + (long long)row * 2112 + 1536; wgt = kw;
        o = ko + (long long)row * 512;          len = 512;
    }
    int t = threadIdx.x;
    float ss = 0.f;
    for (int j = t; j < len; j += 256) { float v = x[j]; ss += v * v; }
    for (int s = 1; s < 64; s <<= 1) ss += __shfl_xor(ss, s);
    __shared__ float red[4];
    int w = t >> 6, lane = t & 63;
    if (lane == 0) red[w] = ss;
    __syncthreads();
    float tot = red[0] + red[1] + red[2] + red[3];
    float r = rsqrtf(tot / (float)len + 1e-6f);
    for (int j = t; j < len; j += 256)
        o[j] = f2bf(bf2f(wgt[j]) * (x[j] * r));
}

// ---------------------------------------------------------------------------
// Rope: deinterleave + rotate.
// ---------------------------------------------------------------------------
__device__ __forceinline__ void rope64(const float* xin, float* xo, int pos) {
    for (int i = 0; i < 32; i++) {
        float ex = (float)(2 * i) * (1.0f / 64.0f);
        float invf = expf(-ex * 9.210340371976184f);  // 10000^-ex
        float ang = (float)pos * invf;
        float sn, cs;
        sincosf(ang, &sn, &cs);
        float a = xin[2 * i], b = xin[2 * i + 1];
        xo[i] = a * cs - b * sn;
        xo[32 + i] = b * cs + a * sn;
    }
}

__global__ __launch_bounds__(256) void rope_q_k(u16* __restrict__ qf) {
    int idx = blockIdx.x * 256 + threadIdx.x;   // 4096*16
    int row = idx >> 4, h = idx & 15, pos = row & 2047;
    u16* p = qf + (long long)row * 3072 + h * 192 + 128;
    uint4 vv[8];
    for (int j = 0; j < 8; j++) vv[j] = ((const uint4*)p)[j];
    const u16* xb = (const u16*)vv;
    float xin[64], xo[64];
    for (int j = 0; j < 64; j++) xin[j] = bf2f(xb[j]);
    rope64(xin, xo, pos);
    uint4 ov[8];
    u16* ob = (u16*)ov;
    for (int j = 0; j < 64; j++) ob[j] = f2bf(xo[j]);
    for (int j = 0; j < 8; j++) ((uint4*)p)[j] = ov[j];
}

__global__ __launch_bounds__(256) void rope_kk(
    const float* __restrict__ base, u16* __restrict__ kr) {
    int row = blockIdx.x * 256 + threadIdx.x;   // 4096
    int pos = row & 2047;
    const float* src = base + (long long)row * 2112 + 2048;
    float4 fv[16];
    for (int j = 0; j < 16; j++) fv[j] = ((const float4*)src)[j];
    const float* xin = (const float*)fv;
    float xo[64];
    rope64(xin, xo, pos);
    uint4 ov[8];
    u16* ob = (u16*)ov;
    for (int j = 0; j < 64; j++) ob[j] = f2bf(xo[j]);
    uint4* dst = (uint4*)(kr + (long long)row * 64);
    for (int j = 0; j < 8; j++) dst[j] = ov[j];
}

// ---------------------------------------------------------------------------
// V^T materialization: Vt[bh][d][s] = kv_up[b*2048+s][h*256+128+d]
// ---------------------------------------------------------------------------
__global__ void transpose_v(const u16* __restrict__ kvup, u16* __restrict__ Vt) {
    __shared__ u16 tile[32][33];
    int bh = blockIdx.z, b = bh >> 4, h = bh & 15;
    int s0 = blockIdx.x * 32, d0 = blockIdx.y * 32;
    int tx = threadIdx.x, ty = threadIdx.y;   // (32,8)
    for (int i = 0; i < 4; i++) {
        int s = s0 + ty + i * 8;
        tile[ty + i * 8][tx] = kvup[(long long)(b * 2048 + s) * 4096 + h * 256 + 128 + d0 + tx];
    }
    __syncthreads();
    for (int i = 0; i < 4; i++) {
        int d = d0 + ty + i * 8;
        Vt[((long long)bh * 128 + d) * 2048 + s0 + tx] = tile[tx][ty + i * 8];
    }
}

#define ATTN_SCALE 0.07216878364870323f   // 1/sqrt(192)

// ---------------------------------------------------------------------------
// Raw scaled scores S = (Q K^T) * scale -> attn region (fp32). Blocks fully
// above the diagonal write their 128x128 tile of zeros (final attn values)
// instead of skipping — this offloads softmax's zero-write pass.
// ---------------------------------------------------------------------------
__global__ __launch_bounds__(256) void scores_gemm(
    const u16* __restrict__ qf, const u16* __restrict__ kvup,
    const u16* __restrict__ krope, float* __restrict__ attn)
{
    int n0 = blockIdx.x * 128, q0 = blockIdx.y * 128;
    int bh = blockIdx.z;
    long long abase = (long long)bh * 4194304;
    int t = threadIdx.x;

    if (n0 > q0) {
        // strictly above diagonal: final attn == 0 here; write it now.
        float4 z4 = {0.f, 0.f, 0.f, 0.f};
        for (int k = 0; k < 16; k++) {
            int fo = t + k * 256;          // float4 index within 128x128 tile
            int tr = fo >> 5;              // tile row
            int tc = (fo & 31) * 4;        // tile col
            *(float4*)(attn + abase + (long long)(q0 + tr) * 2048 + n0 + tc) = z4;
        }
        return;
    }

    int b = bh >> 4, h = bh & 15;
    const u16* qb = qf + (long long)b * 2048 * 3072 + h * 192;
    const u16* kn = kvup + (long long)b * 2048 * 4096 + h * 256;
    const u16* kr = krope + (long long)b * 2048 * 64;

    __shared__ __align__(16) u16 As[128 * 32];
    __shared__ __align__(16) u16 Bs[128 * 32];
    int lane = t & 63, w = t >> 6;
    int sr = t >> 2, sc = (t & 3) * 8;
    int wr = (w >> 1) * 64, wc = (w & 1) * 64;
    int mrow = lane & 15, quad = lane >> 4;

    u16* As0 = &As[t * 8];
    u16* As1 = &As[2048 + t * 8];
    u16* Bs0 = &Bs[t * 8];
    u16* Bs1 = &Bs[2048 + t * 8];

    f32x4 zero = {0.f, 0.f, 0.f, 0.f};
    f32x4 acc[4][4];
    for (int i = 0; i < 4; i++)
        for (int j = 0; j < 4; j++) acc[i][j] = zero;

    for (int k0 = 0; k0 < 192; k0 += 32) {
        const u16* ga0 = qb + (long long)(q0 + sr) * 3072 + k0 + sc;
        const u16* ga1 = ga0 + (long long)64 * 3072;
        const u16 *gb0, *gb1;
        if (k0 < 128) {
            gb0 = kn + (long long)(n0 + sr) * 4096 + k0 + sc;
            gb1 = gb0 + (long long)64 * 4096;
        } else {
            gb0 = kr + (long long)(n0 + sr) * 64 + (k0 - 128) + sc;
            gb1 = gb0 + (long long)64 * 64;
        }
        __syncthreads();
        g2l(ga0, As0);
        g2l(ga1, As1);
        g2l(gb0, Bs0);
        g2l(gb1, Bs1);
        __syncthreads();

        bf16x8 af[4], bfr[4];
        for (int i = 0; i < 4; i++) {
            af[i]  = *(const bf16x8*)(&As[(wr + i * 16 + mrow) * 32 + quad * 8]);
            bfr[i] = *(const bf16x8*)(&Bs[(wc + i * 16 + mrow) * 32 + quad * 8]);
        }
        for (int mt = 0; mt < 4; mt++)
            for (int nt = 0; nt < 4; nt++)
                acc[mt][nt] = mfma16(af[mt], bfr[nt], acc[mt][nt]);
    }

    for (int mt = 0; mt < 4; mt++)
        for (int nt = 0; nt < 4; nt++)
            for (int r = 0; r < 4; r++) {
                int row = q0 + wr + mt * 16 + quad * 4 + r;
                int col = n0 + wc + nt * 16 + mrow;
                attn[abase + (long long)row * 2048 + col] = acc[mt][nt][r] * ATTN_SCALE;
            }
}

// ---------------------------------------------------------------------------
// Row-wise causal softmax, in place over the fp32 attn region. Row lives in
// 8 regs/thread; writes only up to the row's 128-aligned boundary (zeros
// beyond were written by scores_gemm's above-diagonal blocks).
// ---------------------------------------------------------------------------
__global__ __launch_bounds__(256) void softmax_rows(float* __restrict__ attn) {
    int r = blockIdx.x;
    long long bh = blockIdx.y;
    float* p = attn + bh * 4194304LL + (long long)r * 2048;
    int t = threadIdx.x;
    int valid = r + 1;
    int B = ((r >> 7) + 1) << 7;   // 128-aligned end of this row's write region
    int j0 = t * 4;

    float v[8];
    float mx = -INFINITY;
#pragma unroll
    for (int h = 0; h < 2; h++) {
        int j = j0 + h * 1024;
        if (j + 4 <= valid) {
            float4 q = *(const float4*)(p + j);
            v[h * 4 + 0] = q.x; v[h * 4 + 1] = q.y;
            v[h * 4 + 2] = q.z; v[h * 4 + 3] = q.w;
        } else {
#pragma unroll
            for (int k = 0; k < 4; k++) {
                int jj = j + k;
                v[h * 4 + k] = (jj < valid) ? p[jj] : -INFINITY;
            }
        }
#pragma unroll
        for (int k = 0; k < 4; k++) mx = fmaxf(mx, v[h * 4 + k]);
    }
    for (int s = 1; s < 64; s <<= 1) mx = fmaxf(mx, __shfl_xor(mx, s));
    __shared__ float sm[4], s2[4];
    int w = t >> 6;
    if ((t & 63) == 0) sm[w] = mx;
    __syncthreads();
    mx = fmaxf(fmaxf(sm[0], sm[1]), fmaxf(sm[2], sm[3]));

    float ss = 0.f;
#pragma unroll
    for (int i = 0; i < 8; i++) {
        float e = (v[i] == -INFINITY) ? 0.f : expf(v[i] - mx);
        v[i] = e;
        ss += e;
    }
    for (int s = 1; s < 64; s <<= 1) ss += __shfl_xor(ss, s);
    if ((t & 63) == 0) s2[w] = ss;
    __syncthreads();
    ss = s2[0] + s2[1] + s2[2] + s2[3];
    float inv = 1.0f / ss;

#pragma unroll
    for (int h = 0; h < 2; h++) {
        int j = j0 + h * 1024;
        if (j < B) {
            float4 q;
            q.x = v[h * 4 + 0] * inv;
            q.y = v[h * 4 + 1] * inv;
            q.z = v[h * 4 + 2] * inv;
            q.w = v[h * 4 + 3] * inv;
            *(float4*)(p + j) = q;
        }
    }
}

// ---------------------------------------------------------------------------
extern "C" void kernel_launch(void* const* d_in, const int* in_sizes, int n_in,
                              void* d_out, int out_size, void* d_ws, size_t ws_size,
                              hipStream_t stream) {
    (void)in_sizes; (void)n_in; (void)out_size; (void)ws_size;

    const void* r_hidden = d_in[0];
    const void* r_wqd    = d_in[3];
    const void* r_qnw    = d_in[4];
    const void* r_wqu    = d_in[5];
    const void* r_wkvd   = d_in[6];
    const void* r_kvnw   = d_in[7];
    const void* r_wkvu   = d_in[8];
    const void* r_wout   = d_in[9];

    float* out_p  = (float*)d_out;                   // (4096, 2048) fp32
    float* attn_p = (float*)d_out + 8388608LL;       // (32, 2048, 2048) fp32

    char* ws = (char*)d_ws;
    size_t off = 0;
    auto alloc = [&](size_t bytes) { void* p = ws + off; off = (off + bytes + 255) & ~(size_t)255; return p; };

    u32* flags = (u32*)alloc(256);
    // regionA: qc_pre fp32 (4096 x 2112 = 34.6MB); kv_up bf16 aliases after dead
    char* regionA = (char*)alloc(34603008);
    float* qc_pre = (float*)regionA;                 // 4096 x 2112 fp32
    u16* kv_up    = (u16*)regionA;                   // 4096 x 4096 bf16 (33.5MB)
    // regionB: hidden_c (live through step 1); then kv_c (steps 2-4);
    // then Vt (steps 6-9). Lifetimes strictly ordered.
    char* regionB = (char*)alloc(16777216);
    u16* hidden_c = (u16*)regionB;                   // 4096 x 2048 bf16
    u16* kv_c     = (u16*)regionB;                   // 4096 x 512 bf16 (4.2MB)
    u16* Vt       = (u16*)regionB;                   // 32 x 128 x 2048 bf16
    // regionC: q_c only (written step 2, read step 4)
    char* regionC = (char*)alloc(12582912);
    u16* q_c   = (u16*)regionC;                      // 4096 x 1536
    u16* wdown_c = (u16*)alloc(2112LL * 2048 * 2);   // [w_q_down ; w_kv_down]
    // krope reuses wdown_c (dead after step 1; krope written step 3, read step 7)
    u16* krope = wdown_c;                            // 4096 x 64 (0.52MB)
    u16* qnw_c  = (u16*)alloc(1536LL * 2);
    u16* wqu_c  = (u16*)alloc(3072LL * 1536 * 2);
    u16* kvnw_c = (u16*)alloc(512LL * 2);
    u16* wkvu_c = (u16*)alloc(4096LL * 512 * 2);
    u16* wout_c = (u16*)alloc(2048LL * 2048 * 2);
    u16* q_full = (u16*)alloc(4096LL * 3072 * 2);    // Obuf aliases after scores
    u16* Obuf   = q_full;                            // 16.8MB <= 25.2MB

    // --- dtype detection ---
    DetectArgs da;
    da.p[0] = r_hidden; da.n[0] = 8388608;
    da.p[1] = r_wqd;    da.n[1] = 3145728;
    da.p[2] = r_qnw;    da.n[2] = 1536;
    da.p[3] = r_wqu;    da.n[3] = 4718592;
    da.p[4] = r_wkvd;   da.n[4] = 1179648;
    da.p[5] = r_kvnw;   da.n[5] = 512;
    da.p[6] = r_wkvu;   da.n[6] = 2097152;
    da.p[7] = r_wout;   da.n[7] = 4194304;
    hipLaunchKernelGGL(detect_k, dim3(8), dim3(256), 0, stream, da, flags);

    // --- single merged conversion dispatch ---
    ConvArgs ca;
    ca.src[0] = r_hidden; ca.dst[0] = hidden_c;            ca.n[0] = 8388608;
    ca.src[1] = r_wqd;    ca.dst[1] = wdown_c;             ca.n[1] = 3145728;
    ca.src[2] = r_qnw;    ca.dst[2] = qnw_c;               ca.n[2] = 1536;
    ca.src[3] = r_wqu;    ca.dst[3] = wqu_c;               ca.n[3] = 4718592;
    ca.src[4] = r_wkvd;   ca.dst[4] = wdown_c + 3145728;   ca.n[4] = 1179648;
    ca.src[5] = r_kvnw;   ca.dst[5] = kvnw_c;              ca.n[5] = 512;
    ca.src[6] = r_wkvu;   ca.dst[6] = wkvu_c;              ca.n[6] = 2097152;
    ca.src[7] = r_wout;   ca.dst[7] = wout_c;              ca.n[7] = 4194304;
    ca.pre[0] = 0;
    for (int i = 0; i < 8; i++) ca.pre[i + 1] = ca.pre[i] + (ca.n[i] + 1023) / 1024;
    hipLaunchKernelGGL(convert_all, dim3(ca.pre[8]), dim3(256), 0, stream, ca, flags);

    // 1. qc_pre = hidden @ [w_q_down ; w_kv_down]^T  (merged, N=2112, fp32)
    //    After this: hidden_c dead (regionB free), wdown_c dead (krope scratch).
    hipLaunchKernelGGL(gemm128, dim3(17, 32, 1), dim3(256), 0, stream,
        hidden_c, 2048, 0LL, wdown_c, 2048, 0LL, (u16*)nullptr, qc_pre, 2112, 0LL, 0LL, 2112, 2048);
    // 2. merged rmsnorm: q -> q_c (regionC), kv -> kv_c (regionB; disjoint)
    hipLaunchKernelGGL(rmsnorm2_k, dim3(4096, 2), dim3(256), 0, stream,
        qc_pre, qnw_c, kvnw_c, q_c, kv_c);
    // 3. k_rope = rope(qc_pre[:, 2048:2112]) -> krope (wdown_c scratch)
    hipLaunchKernelGGL(rope_kk, dim3(16), dim3(256), 0, stream, qc_pre, krope);
    // 4. dual GEMM: q_full = q_c @ w_q_up^T (z=0) and kv_up = kv_c @ w_kv_up^T (z=1)
    //    (qc_pre dead -> kv_up may overwrite regionA)
    DualGemm dg;
    dg.X[0] = q_c;   dg.xRow[0] = 1536; dg.W[0] = wqu_c;  dg.wRow[0] = 1536;
    dg.C[0] = q_full; dg.cRow[0] = 3072; dg.N[0] = 3072;  dg.K[0] = 1536; dg.xmax[0] = 24;
    dg.X[1] = kv_c;  dg.xRow[1] = 512;  dg.W[1] = wkvu_c; dg.wRow[1] = 512;
    dg.C[1] = kv_up; dg.cRow[1] = 4096; dg.N[1] = 4096;   dg.K[1] = 512;  dg.xmax[1] = 32;
    hipLaunchKernelGGL(gemm128_dual, dim3(32, 32, 2), dim3(256), 0, stream, dg);
    // 5. rope on q (in place)
    hipLaunchKernelGGL(rope_q_k, dim3(256), dim3(256), 0, stream, q_full);
    // 6. Vt[bh][d][s]  (regionB reuse; kv_c dead after step 4)
    hipLaunchKernelGGL(transpose_v, dim3(64, 4, 32), dim3(32, 8), 0, stream, kv_up, Vt);
    // 7. raw scaled scores + above-diagonal zeros -> attn region (fp32)
    hipLaunchKernelGGL(scores_gemm, dim3(16, 16, 32), dim3(256), 0, stream,
        q_full, kv_up, krope, attn_p);
    // 8. row-wise causal softmax in place (bounded write)
    hipLaunchKernelGGL(softmax_rows, dim3(2048, 32), dim3(256), 0, stream, attn_p);
    // 9. O = attn @ V (batched over bh); heavy tiles first
    hipLaunchKernelGGL(gemm128_xf32, dim3(1, 16, 32), dim3(256), 0, stream,
        attn_p, 2048, 4194304LL, Vt, 2048, 262144LL, Obuf,
        2048, 4194304LL, 128LL, 128, 2048);
    // 10. out = O @ w_out^T (fp32 out)
    hipLaunchKernelGGL(gemm128, dim3(16, 32, 1), dim3(256), 0, stream,
        Obuf, 2048, 0LL, wout_c, 2048, 0LL, (u16*)nullptr, out_p, 2048, 0LL, 0LL, 2048, 2048);
}